// Round 16
// baseline (478.233 us; speedup 1.0000x reference)
//
#include <hip/hip_runtime.h>
#include <math.h>

// Problem constants
#define B_    4096
#define D_    2048
#define K_    16384
#define SIDE  128

// f32-fallback GEMM tiling
#define BM 128
#define BN 128
#define BD 16
#define ASTR 132

// Argmin refinement
#define EPS_CAND 0.04f
#define MARGIN   0.015f
#define MAXCAND  64
#define RMAX     12

// GEMM (round-8 structure + early-stage hoist): BK=64, one barrier per tile
#define NKT 32   // 2048 / 64

typedef __attribute__((ext_vector_type(8))) short bf16x8;
typedef __attribute__((ext_vector_type(4))) float f32x4;

__device__ __forceinline__ short bf16_rne(float f) {
    unsigned u = __float_as_uint(f);
    unsigned r = u + 0x7FFFu + ((u >> 16) & 1u);
    return (short)(r >> 16);
}

__device__ __forceinline__ void gload16(const void* g, void* l) {
    __builtin_amdgcn_global_load_lds(
        (const __attribute__((address_space(1))) unsigned int*)g,
        (__attribute__((address_space(3))) unsigned int*)l, 16, 0, 0);
}

// ---------------- pack kernel -> Bt (bf16 transposed) + k2 partials, fused ----------------
__global__ __launch_bounds__(256) void pack_bt_k2(const float* __restrict__ kmat,
                                                  short* __restrict__ Bt,
                                                  float* __restrict__ pk2b) {
    __shared__ float tile[64][65];
    const int n0 = blockIdx.x * 64, d0 = blockIdx.y * 64;
    const int t = threadIdx.x;
    const int lr = t >> 4, lc4 = (t & 15) * 4;
    #pragma unroll
    for (int r = 0; r < 4; ++r) {
        float4 v = *(const float4*)&kmat[(size_t)(d0 + lr + r*16) * K_ + n0 + lc4];
        tile[lr + r*16][lc4 + 0] = v.x;
        tile[lr + r*16][lc4 + 1] = v.y;
        tile[lr + r*16][lc4 + 2] = v.z;
        tile[lr + r*16][lc4 + 3] = v.w;
    }
    __syncthreads();
    const int n = t >> 2, dc = (t & 3) * 16;
    short tmp[16];
    float s = 0.f;
    #pragma unroll
    for (int i = 0; i < 16; ++i) {
        float v = tile[dc + i][n];
        tmp[i] = bf16_rne(v);
        s = fmaf(v, v, s);
    }
    short* dst = &Bt[(size_t)(n0 + n) * 2048 + d0 + dc];
    *(int4*)dst       = *(const int4*)tmp;
    *(int4*)(dst + 8) = *(const int4*)(tmp + 8);
    s += __shfl_xor(s, 1);
    s += __shfl_xor(s, 2);
    if ((t & 3) == 0) pk2b[(size_t)(d0 >> 6) * K_ + n0 + n] = s;
}

// ---------------- fused: pack x -> Ah + x2 (blocks < 4096) | k2 reduce (blocks >= 4096) ----
__global__ __launch_bounds__(256) void pack_a_k2(const float* __restrict__ x,
                                                 short* __restrict__ Ah,
                                                 float* __restrict__ x2,
                                                 const float* __restrict__ pk2b,
                                                 float* __restrict__ k2) {
    const int b = blockIdx.x;
    const int t = threadIdx.x;
    if (b < B_) {
        const size_t i = (size_t)b * 2048 + (size_t)t * 8;
        float4 v0 = *(const float4*)&x[i];
        float4 v1 = *(const float4*)&x[i + 4];
        short tmp[8] = { bf16_rne(v0.x), bf16_rne(v0.y), bf16_rne(v0.z), bf16_rne(v0.w),
                         bf16_rne(v1.x), bf16_rne(v1.y), bf16_rne(v1.z), bf16_rne(v1.w) };
        *(int4*)&Ah[i] = *(const int4*)tmp;
        float s = v0.x*v0.x + v0.y*v0.y + v0.z*v0.z + v0.w*v0.w
                + v1.x*v1.x + v1.y*v1.y + v1.z*v1.z + v1.w*v1.w;
        __shared__ float red[256];
        red[t] = s; __syncthreads();
        for (int off = 128; off > 0; off >>= 1) {
            if (t < off) red[t] += red[t + off];
            __syncthreads();
        }
        if (t == 0) x2[b] = red[0];
    } else {
        const int k = (b - B_) * 256 + t;
        float s = 0.f;
        #pragma unroll
        for (int j = 0; j < 32; ++j) s += pk2b[(size_t)j * K_ + k];
        k2[k] = s;
    }
}

// ---------------- pipelined 256x256 bf16 MFMA GEMM -> norms2 -> d_out + pmin ----------------
// r8 structure with staging hoisted to tile top: the 16 gloads for tile t+1 get
// ~300 extra cycles of cover before the tile-end vmcnt(0) drain.
// pmin layout: [64 n-blocks][4096 rows]
__global__ __launch_bounds__(512, 2) void gemm_8ph(
    const short* __restrict__ Ah, const short* __restrict__ Bt,
    const float* __restrict__ x2, const float* __restrict__ k2,
    float* __restrict__ out, float* __restrict__ pmin)
{
    __shared__ short As[4 * 8192];
    __shared__ short Bs[4 * 8192];

    const int tid = threadIdx.x;
    const int lane = tid & 63;
    const int w = tid >> 6;
    const int wm = w >> 2, wn = w & 3;
    const int lrow = lane & 15, lkg = lane >> 4;

    // XCD-aware swizzle: 1024 blocks = 8 xcds x (8 bn-chunk x 16 bm)
    const int orig = blockIdx.x;
    const int xcd = orig & 7, seq = orig >> 3;
    const int bn0 = (xcd * 8 + (seq & 7)) * 256;
    const int bm0 = (seq >> 3) * 256;

    const int csw = ((tid & 3) ^ ((tid >> 3) & 3)) * 8;   // pre-swizzled source chunk
    const short* pA = Ah + (size_t)(bm0 + (tid >> 2)) * 2048 + csw;
    const short* pB = Bt + (size_t)(bn0 + (tid >> 2)) * 2048 + csw;
    const int ldsT = tid * 8;

    const int rsw = (lkg ^ ((lrow >> 1) & 3)) * 8;        // read-side swizzle
    const int aBase = (wm * 128 + lrow) * 32 + rsw;
    const int bBase = (wn * 64 + lrow) * 32 + rsw;

    f32x4 acc[8][4];
    #pragma unroll
    for (int i = 0; i < 8; ++i)
        #pragma unroll
        for (int j = 0; j < 4; ++j) acc[i][j] = (f32x4){0.f, 0.f, 0.f, 0.f};

#define STAGE(MATL, PTR, KS, T) do { \
    short* _l = (MATL) + ((((T) & 1) * 2 + (KS)) * 8192) + ldsT; \
    const short* _g = (PTR) + (size_t)(T) * 64 + (KS) * 32; \
    gload16(_g, _l); \
    gload16(_g + (size_t)128 * 2048, _l + 4096); \
} while (0)

    // prologue: stage tile 0 (both ksub halves of A and B), drain, barrier
    STAGE(As, pA, 0, 0); STAGE(As, pA, 1, 0);
    STAGE(Bs, pB, 0, 0); STAGE(Bs, pB, 1, 0);
    asm volatile("s_waitcnt vmcnt(0)" ::: "memory");
    __builtin_amdgcn_s_barrier();

    for (int t = 0; t < NKT; ++t) {
        const int rg = (t & 1) * 2;
        const short* Ar0 = &As[rg * 8192];
        const short* Br0 = &Bs[rg * 8192];
        const short* Ar1 = Ar0 + 8192;
        const short* Br1 = Br0 + 8192;
        bf16x8 a0[8], b0[4], a1[8], b1[4];

        // stage tile t+1 FIRST — maximum latency cover before the tile-end drain
        if (t + 1 < NKT) {
            STAGE(As, pA, 0, t + 1); STAGE(As, pA, 1, t + 1);
            STAGE(Bs, pB, 0, t + 1); STAGE(Bs, pB, 1, t + 1);
        }
        __builtin_amdgcn_sched_barrier(0);

        // group 0 reads (ksub0)
        #pragma unroll
        for (int mf = 0; mf < 8; ++mf) a0[mf] = *(const bf16x8*)&Ar0[aBase + mf * 512];
        #pragma unroll
        for (int nf = 0; nf < 4; ++nf) b0[nf] = *(const bf16x8*)&Br0[bBase + nf * 512];
        __builtin_amdgcn_sched_barrier(0);
        // group 1 reads (ksub1) — overlap MFMA ksub0 via compiler lgkmcnt
        #pragma unroll
        for (int mf = 0; mf < 8; ++mf) a1[mf] = *(const bf16x8*)&Ar1[aBase + mf * 512];
        #pragma unroll
        for (int nf = 0; nf < 4; ++nf) b1[nf] = *(const bf16x8*)&Br1[bBase + nf * 512];
        __builtin_amdgcn_sched_barrier(0);

        __builtin_amdgcn_s_setprio(1);
        #pragma unroll
        for (int mf = 0; mf < 8; ++mf) {
            acc[mf][0] = __builtin_amdgcn_mfma_f32_16x16x32_bf16(a0[mf], b0[0], acc[mf][0], 0, 0, 0);
            acc[mf][1] = __builtin_amdgcn_mfma_f32_16x16x32_bf16(a0[mf], b0[1], acc[mf][1], 0, 0, 0);
            acc[mf][2] = __builtin_amdgcn_mfma_f32_16x16x32_bf16(a0[mf], b0[2], acc[mf][2], 0, 0, 0);
            acc[mf][3] = __builtin_amdgcn_mfma_f32_16x16x32_bf16(a0[mf], b0[3], acc[mf][3], 0, 0, 0);
        }
        __builtin_amdgcn_sched_barrier(0);
        #pragma unroll
        for (int mf = 0; mf < 8; ++mf) {
            acc[mf][0] = __builtin_amdgcn_mfma_f32_16x16x32_bf16(a1[mf], b1[0], acc[mf][0], 0, 0, 0);
            acc[mf][1] = __builtin_amdgcn_mfma_f32_16x16x32_bf16(a1[mf], b1[1], acc[mf][1], 0, 0, 0);
            acc[mf][2] = __builtin_amdgcn_mfma_f32_16x16x32_bf16(a1[mf], b1[2], acc[mf][2], 0, 0, 0);
            acc[mf][3] = __builtin_amdgcn_mfma_f32_16x16x32_bf16(a1[mf], b1[3], acc[mf][3], 0, 0, 0);
        }
        __builtin_amdgcn_s_setprio(0);
        __builtin_amdgcn_sched_barrier(0);
        asm volatile("s_waitcnt vmcnt(0)" ::: "memory");
        __builtin_amdgcn_s_barrier();
    }
#undef STAGE

    // ---- epilogue: norms2 scalar stores + register/shfl per-row block-min ----
    // C/D frag: col = lane&15, row = (lane>>4)*4 + j
    const int r0 = bm0 + wm * 128 + lkg * 4;
    const int c0 = bn0 + wn * 64 + lrow;
    float kc[4];
    #pragma unroll
    for (int nf = 0; nf < 4; ++nf) kc[nf] = k2[c0 + nf * 16];

    float* sm2 = (float*)As;   // [4 wn][256 rows] = 4 KB, reuse staging LDS
    __syncthreads();

    #pragma unroll
    for (int mf = 0; mf < 8; ++mf) {
        #pragma unroll
        for (int jj = 0; jj < 4; ++jj) {
            const int gr = r0 + mf * 16 + jj;
            const float xv = x2[gr];
            float* orow = out + (size_t)gr * K_ + c0;
            float v0 = fmaxf((xv - 2.f * acc[mf][0][jj]) + kc[0], 0.f);
            float v1 = fmaxf((xv - 2.f * acc[mf][1][jj]) + kc[1], 0.f);
            float v2 = fmaxf((xv - 2.f * acc[mf][2][jj]) + kc[2], 0.f);
            float v3 = fmaxf((xv - 2.f * acc[mf][3][jj]) + kc[3], 0.f);
            orow[0]  = v0;
            orow[16] = v1;
            orow[32] = v2;
            orow[48] = v3;
            float m = fminf(fminf(v0, v1), fminf(v2, v3));
            m = fminf(m, __shfl_xor(m, 1));
            m = fminf(m, __shfl_xor(m, 2));
            m = fminf(m, __shfl_xor(m, 4));
            m = fminf(m, __shfl_xor(m, 8));
            if (lrow == 0)
                sm2[wn * 256 + wm * 128 + mf * 16 + lkg * 4 + jj] = m;
        }
    }
    __syncthreads();
    if (tid < 256) {
        float m = fminf(fminf(sm2[tid], sm2[256 + tid]),
                        fminf(sm2[512 + tid], sm2[768 + tid]));
        pmin[(size_t)(bn0 >> 8) * 4096 + bm0 + tid] = m;
    }
}

// ---------------- fused rowmin/candidates/refine + patch-radial write ----------------
__global__ __launch_bounds__(256) void rowpost(
    float* __restrict__ out, const float* __restrict__ X,
    const float* __restrict__ Kmat, const float* __restrict__ pmin,
    const float* __restrict__ sigma)
{
    const int row = blockIdx.x;
    const int t = threadIdx.x;
    float* orow = out + (size_t)row * K_;

    __shared__ float sblk[64];
    __shared__ float sgmin;
    __shared__ int scnt, swidx, needRefine;
    __shared__ int cand[MAXCAND];
    __shared__ float cval[MAXCAND];
    __shared__ double sred[256];
    __shared__ float cscore[MAXCAND];
    __shared__ float patch[(2*RMAX+1)*(2*RMAX+1)];

    if (t < 64) sblk[t] = pmin[(size_t)t * 4096 + row];
    if (t == 0) scnt = 0;
    __syncthreads();
    if (t == 0) {
        float m = sblk[0];
        for (int i = 1; i < 64; ++i) m = fminf(m, sblk[i]);
        sgmin = m;
    }
    __syncthreads();
    const float thr = sgmin + EPS_CAND;

    // candidate collection: only blocks whose min can reach thr
    for (int b = 0; b < 64; ++b) {
        if (sblk[b] <= thr) {
            float v = orow[b * 256 + t];
            if (v <= thr) {
                int p = atomicAdd(&scnt, 1);
                if (p < MAXCAND) { cand[p] = b * 256 + t; cval[p] = v; }
            }
        }
    }
    __syncthreads();
    const int cnt = min(scnt, MAXCAND);

    if (cnt == 1) {
        if (t == 0) { swidx = cand[0]; needRefine = 0; }
        __syncthreads();
    } else {
        // stored-margin test: if stored best leads by > MARGIN, it is the gold winner
        if (t == 0) {
            float bv = cval[0]; int bi = cand[0];
            for (int c = 1; c < cnt; ++c)
                if (cval[c] < bv || (cval[c] == bv && cand[c] < bi)) { bv = cval[c]; bi = cand[c]; }
            float sv = 3.4e38f;
            for (int c = 0; c < cnt; ++c)
                if (cand[c] != bi) sv = fminf(sv, cval[c]);
            if (sv - bv > MARGIN) { swidx = bi; needRefine = 0; }
            else needRefine = 1;
        }
        __syncthreads();
        if (needRefine) {
            // gold emulation: each primitive exact-f64, then f32-rounded
            const float* xrow = X + (size_t)row * D_;
            double xs = 0.0;
            for (int d = t; d < D_; d += 256) {
                float xv = xrow[d];
                float sq = xv * xv;
                xs += (double)sq;
            }
            sred[t] = xs; __syncthreads();
            for (int off = 128; off > 0; off >>= 1) {
                if (t < off) sred[t] += sred[t + off];
                __syncthreads();
            }
            const float x2f = (float)sred[0];
            __syncthreads();

            for (int c = 0; c < cnt; ++c) {
                const int k = cand[c];
                double dt = 0.0, kk = 0.0;
                for (int d = t; d < D_; d += 256) {
                    float wv = Kmat[(size_t)d * K_ + k];
                    float xv = xrow[d];
                    dt += (double)xv * (double)wv;
                    float w2 = wv * wv;
                    kk += (double)w2;
                }
                sred[t] = dt; __syncthreads();
                for (int off = 128; off > 0; off >>= 1) {
                    if (t < off) sred[t] += sred[t + off];
                    __syncthreads();
                }
                const float dotf = (float)sred[0];
                __syncthreads();
                sred[t] = kk; __syncthreads();
                for (int off = 128; off > 0; off >>= 1) {
                    if (t < off) sred[t] += sred[t + off];
                    __syncthreads();
                }
                if (t == 0) {
                    const float k2f = (float)sred[0];
                    cscore[c] = fmaxf((x2f - 2.0f * dotf) + k2f, 0.0f);
                }
                __syncthreads();
            }
            if (t == 0) {
                float bv = cscore[0]; int bi = cand[0];
                for (int c = 1; c < cnt; ++c) {
                    if (cscore[c] < bv || (cscore[c] == bv && cand[c] < bi)) {
                        bv = cscore[c]; bi = cand[c];
                    }
                }
                swidx = bi;
            }
            __syncthreads();
        }
    }

    // ---- radial write: values outside radius R are < 0.5 -> write zeros, skip read ----
    const int wi = swidx;
    const int wx = wi >> 7, wy = wi & 127;
    const float sg = sigma[0];
    const float ninv  = -0.5f / (sg * sg);
    const float scale = 1.0f / (sg * sqrtf(2.0f * 3.14159265358979323846f));
    // drop bound: scale*exp(-R^2/(2 sg^2))*4096 <= 0.5
    float larg = 8192.0f * scale;
    int R = (larg <= 1.0f) ? 0
          : (int)ceilf(sg * sqrtf(2.0f * logf(larg)));

    if (R <= RMAX) {
        const int W = 2 * R + 1;
        for (int p = t; p < W * W; p += 256) {
            int dx = p / W - R, dy = p % W - R;
            int gx = wx + dx, gy = wy + dy;
            if ((unsigned)gx < 128u && (unsigned)gy < 128u)
                patch[p] = orow[gx * 128 + gy];
        }
        __syncthreads();
        for (int i = t; i < K_ / 4; i += 256) {
            const int k0 = i * 4;
            const int gx = k0 >> 7;
            const int dx = gx - wx;
            float4 v = make_float4(0.f, 0.f, 0.f, 0.f);
            float* vp = (float*)&v;
            if (dx >= -R && dx <= R) {
                #pragma unroll
                for (int j = 0; j < 4; ++j) {
                    int gy = (k0 & 127) + j;
                    int dy = gy - wy;
                    if (dy >= -R && dy <= R) {
                        float d2 = (float)(dx * dx + dy * dy);
                        vp[j] = patch[(dx + R) * W + (dy + R)] * (scale * __expf(ninv * d2));
                    }
                }
            }
            *(float4*)&orow[k0] = v;
        }
    } else {
        // general-sigma fallback: full read-modify-write
        for (int i = t; i < K_ / 4; i += 256) {
            float4 v = ((const float4*)orow)[i];
            float* vp = (float*)&v;
            #pragma unroll
            for (int j = 0; j < 4; ++j) {
                int k = i * 4 + j;
                float gx = (float)(k >> 7), gy = (float)(k & 127);
                float dx = gx - (float)wx, dy = gy - (float)wy;
                float d2 = dx * dx + dy * dy;
                vp[j] = vp[j] * (__expf(ninv * d2) * scale);
            }
            ((float4*)orow)[i] = v;
        }
    }
}

// ================= f32 fallback path (unchanged round-3 kernels) =================
__global__ void k2_partial(const float* __restrict__ kmat, float* __restrict__ pk2) {
    int k  = blockIdx.x * 256 + threadIdx.x;
    int d0 = blockIdx.y * 256;
    float s = 0.f;
    #pragma unroll 8
    for (int d = 0; d < 256; ++d) {
        float v = kmat[(size_t)(d0 + d) * K_ + k];
        s = fmaf(v, v, s);
    }
    pk2[(size_t)blockIdx.y * K_ + k] = s;
}

__global__ void k2_reduce(const float* __restrict__ pk2, float* __restrict__ k2) {
    int k = blockIdx.x * 256 + threadIdx.x;
    float s = 0.f;
    #pragma unroll
    for (int j = 0; j < 8; ++j) s += pk2[(size_t)j * K_ + k];
    k2[k] = s;
}

__global__ void x2_kernel(const float* __restrict__ x, float* __restrict__ x2) {
    int row = blockIdx.x;
    const float* xr = x + (size_t)row * D_;
    int t = threadIdx.x;
    float4 v0 = ((const float4*)xr)[t];
    float4 v1 = ((const float4*)xr)[t + 256];
    float s = v0.x*v0.x + v0.y*v0.y + v0.z*v0.z + v0.w*v0.w
            + v1.x*v1.x + v1.y*v1.y + v1.z*v1.z + v1.w*v1.w;
    __shared__ float red[256];
    red[t] = s; __syncthreads();
    for (int off = 128; off > 0; off >>= 1) {
        if (t < off) red[t] += red[t + off];
        __syncthreads();
    }
    if (t == 0) x2[row] = red[0];
}

__global__ __launch_bounds__(256) void gemm_norms(
    const float* __restrict__ X, const float* __restrict__ Kmat,
    const float* __restrict__ x2, const float* __restrict__ k2,
    float* __restrict__ out)
{
    __shared__ float Asf[BD * ASTR];
    __shared__ float Bsf[BD * BN];

    const int tid = threadIdx.x;
    const int tx = tid & 15, ty = tid >> 4;
    const int bn0 = blockIdx.x * BN;
    const int bm0 = blockIdx.y * BM;

    float acc[8][8];
    #pragma unroll
    for (int i = 0; i < 8; ++i)
        #pragma unroll
        for (int j = 0; j < 8; ++j) acc[i][j] = 0.f;

    const int lm = tid >> 2;
    const int ld = (tid & 3) << 2;
    const int bd = tid >> 5;
    const int bk = (tid & 31) << 2;

    const float* Xp = X    + (size_t)(bm0 + lm) * D_ + ld;
    const float* Kp = Kmat + (size_t)bd * K_ + bn0 + bk;

    float4 a0 = *(const float4*)(Xp);
    float4 a1 = *(const float4*)(Xp + (size_t)64 * D_);
    float4 b0 = *(const float4*)(Kp);
    float4 b1 = *(const float4*)(Kp + (size_t)8 * K_);

    const int NT = D_ / BD;
    for (int kt = 0; kt < NT; ++kt) {
        __syncthreads();
        Asf[(ld+0)*ASTR + lm]      = a0.x;
        Asf[(ld+1)*ASTR + lm]      = a0.y;
        Asf[(ld+2)*ASTR + lm]      = a0.z;
        Asf[(ld+3)*ASTR + lm]      = a0.w;
        Asf[(ld+0)*ASTR + lm + 64] = a1.x;
        Asf[(ld+1)*ASTR + lm + 64] = a1.y;
        Asf[(ld+2)*ASTR + lm + 64] = a1.z;
        Asf[(ld+3)*ASTR + lm + 64] = a1.w;
        *(float4*)&Bsf[bd*BN + bk]     = b0;
        *(float4*)&Bsf[(bd+8)*BN + bk] = b1;
        __syncthreads();

        if (kt + 1 < NT) {
            const float* Xn = Xp + (kt + 1) * BD;
            const float* Kn = Kp + (size_t)(kt + 1) * BD * K_;
            a0 = *(const float4*)(Xn);
            a1 = *(const float4*)(Xn + (size_t)64 * D_);
            b0 = *(const float4*)(Kn);
            b1 = *(const float4*)(Kn + (size_t)8 * K_);
        }

        #pragma unroll
        for (int dd = 0; dd < BD; ++dd) {
            float4 A0 = *(const float4*)&Asf[dd*ASTR + ty*4];
            float4 A1 = *(const float4*)&Asf[dd*ASTR + ty*4 + 64];
            float4 B0 = *(const float4*)&Bsf[dd*BN + tx*4];
            float4 B1 = *(const float4*)&Bsf[dd*BN + tx*4 + 64];
            float a[8] = {A0.x,A0.y,A0.z,A0.w,A1.x,A1.y,A1.z,A1.w};
            float b[8] = {B0.x,B0.y,B0.z,B0.w,B1.x,B1.y,B1.z,B1.w};
            #pragma unroll
            for (int i = 0; i < 8; ++i)
                #pragma unroll
                for (int j = 0; j < 8; ++j)
                    acc[i][j] = fmaf(a[i], b[j], acc[i][j]);
        }
    }

    int rl[8], cl[8];
    #pragma unroll
    for (int i = 0; i < 4; ++i) {
        rl[i] = ty*4 + i;  rl[i+4] = ty*4 + 64 + i;
        cl[i] = tx*4 + i;  cl[i+4] = tx*4 + 64 + i;
    }
    float xr[8], kc[8];
    #pragma unroll
    for (int i = 0; i < 8; ++i) { xr[i] = x2[bm0 + rl[i]]; kc[i] = k2[bn0 + cl[i]]; }

    #pragma unroll
    for (int i = 0; i < 8; ++i) {
        float vv[8];
        #pragma unroll
        for (int j = 0; j < 8; ++j)
            vv[j] = fmaxf((xr[i] - 2.f * acc[i][j]) + kc[j], 0.f);
        int gr = bm0 + rl[i];
        *(float4*)&out[(size_t)gr * K_ + bn0 + tx*4]      = make_float4(vv[0],vv[1],vv[2],vv[3]);
        *(float4*)&out[(size_t)gr * K_ + bn0 + tx*4 + 64] = make_float4(vv[4],vv[5],vv[6],vv[7]);
    }
}

__global__ __launch_bounds__(256) void rowscan(
    const float* __restrict__ out, const float* __restrict__ X,
    const float* __restrict__ Kmat, int* __restrict__ widx)
{
    const int row = blockIdx.x;
    const int t = threadIdx.x;
    const float* orow = out + (size_t)row * K_;

    float mn = 3.4e38f;
    for (int i = t; i < K_/4; i += 256) {
        float4 v = ((const float4*)orow)[i];
        mn = fminf(mn, fminf(fminf(v.x, v.y), fminf(v.z, v.w)));
    }
    __shared__ float smin[256];
    smin[t] = mn; __syncthreads();
    for (int off = 128; off > 0; off >>= 1) {
        if (t < off) smin[t] = fminf(smin[t], smin[t+off]);
        __syncthreads();
    }
    const float rowmin = smin[0];

    __shared__ int scnt;
    __shared__ int cand[MAXCAND];
    if (t == 0) scnt = 0;
    __syncthreads();
    const float thr = rowmin + EPS_CAND;
    for (int i = t; i < K_/4; i += 256) {
        float4 v = ((const float4*)orow)[i];
        float vv[4] = {v.x, v.y, v.z, v.w};
        #pragma unroll
        for (int j = 0; j < 4; ++j) {
            if (vv[j] <= thr) {
                int p = atomicAdd(&scnt, 1);
                if (p < MAXCAND) cand[p] = i*4 + j;
            }
        }
    }
    __syncthreads();
    const int cnt = min(scnt, MAXCAND);
    if (cnt == 1) {
        if (t == 0) widx[row] = cand[0];
        return;
    }

    const float* xrow = X + (size_t)row * D_;
    __shared__ double sred[256];
    double xs = 0.0;
    for (int d = t; d < D_; d += 256) {
        float xv = xrow[d];
        float sq = xv * xv;
        xs += (double)sq;
    }
    sred[t] = xs; __syncthreads();
    for (int off = 128; off > 0; off >>= 1) {
        if (t < off) sred[t] += sred[t+off];
        __syncthreads();
    }
    const float x2f = (float)sred[0];
    __syncthreads();

    __shared__ float cscore[MAXCAND];
    for (int c = 0; c < cnt; ++c) {
        const int k = cand[c];
        double dt = 0.0, kk = 0.0;
        for (int d = t; d < D_; d += 256) {
            float wv = Kmat[(size_t)d * K_ + k];
            float xv = xrow[d];
            dt += (double)xv * (double)wv;
            float w2 = wv * wv;
            kk += (double)w2;
        }
        sred[t] = dt; __syncthreads();
        for (int off = 128; off > 0; off >>= 1) {
            if (t < off) sred[t] += sred[t+off];
            __syncthreads();
        }
        const float dotf = (float)sred[0];
        __syncthreads();
        sred[t] = kk; __syncthreads();
        for (int off = 128; off > 0; off >>= 1) {
            if (t < off) sred[t] += sred[t+off];
            __syncthreads();
        }
        if (t == 0) {
            const float k2f = (float)sred[0];
            cscore[c] = fmaxf((x2f - 2.0f * dotf) + k2f, 0.0f);
        }
        __syncthreads();
    }
    if (t == 0) {
        float bv = cscore[0]; int bi = cand[0];
        for (int c = 1; c < cnt; ++c) {
            if (cscore[c] < bv || (cscore[c] == bv && cand[c] < bi)) {
                bv = cscore[c]; bi = cand[c];
            }
        }
        widx[row] = bi;
    }
}

__global__ void finalize(float* __restrict__ out, const int* __restrict__ widx,
                         const float* __restrict__ sigma) {
    size_t gid = (size_t)blockIdx.x * blockDim.x + threadIdx.x;
    int row = (int)(gid / (K_ / 4));
    int c4  = (int)(gid % (K_ / 4)) * 4;
    int w = widx[row];
    float wx = (float)(w >> 7), wy = (float)(w & 127);
    float sg = sigma[0];
    float ninv  = -0.5f / (sg * sg);
    float scale = 1.0f / (sg * sqrtf(2.0f * 3.14159265358979323846f));
    float4 v = *(float4*)&out[(size_t)row * K_ + c4];
    float* vp = (float*)&v;
    #pragma unroll
    for (int j = 0; j < 4; ++j) {
        int k = c4 + j;
        float gx = (float)(k >> 7), gy = (float)(k & 127);
        float dx = gx - wx, dy = gy - wy;
        float d2 = dx*dx + dy*dy;
        vp[j] = vp[j] * (__expf(ninv * d2) * scale);
    }
    *(float4*)&out[(size_t)row * K_ + c4] = v;
}

extern "C" void kernel_launch(void* const* d_in, const int* in_sizes, int n_in,
                              void* d_out, int out_size, void* d_ws, size_t ws_size,
                              hipStream_t stream) {
    const float* x     = (const float*)d_in[0];
    const float* kmat  = (const float*)d_in[1];
    const float* sigma = (const float*)d_in[2];
    float* out = (float*)d_out;

    const size_t BT_BYTES = (size_t)K_ * D_ * 2;   // 64 MB
    const size_t AH_BYTES = (size_t)B_ * D_ * 2;   // 16 MB
    // floats after Bt|Ah: k2[16384] x2[4096] pk2b[32*16384] pmin[64*4096]
    const size_t WS_NEED  = BT_BYTES + AH_BYTES +
        (size_t)(16384 + 4096 + 32*16384 + 64*4096) * 4;

    if (ws_size >= WS_NEED) {
        short* Bt   = (short*)d_ws;
        short* Ahp  = (short*)((char*)d_ws + BT_BYTES);
        float* k2   = (float*)((char*)d_ws + BT_BYTES + AH_BYTES);
        float* x2   = k2 + 16384;
        float* pk2b = x2 + 4096;
        float* pmin = pk2b + 32*16384;

        pack_bt_k2<<<dim3(K_/64, D_/64), 256, 0, stream>>>(kmat, Bt, pk2b);
        pack_a_k2 <<<B_ + K_/256, 256, 0, stream>>>(x, Ahp, x2, pk2b, k2);
        gemm_8ph  <<<1024, 512, 0, stream>>>(Ahp, Bt, x2, k2, out, pmin);
        rowpost   <<<B_, 256, 0, stream>>>(out, x, kmat, pmin, sigma);
    } else {
        float* ws = (float*)d_ws;
        float* k2   = ws;
        float* x2   = ws + 16384;
        int*   widx = (int*)(ws + 20480);
        float* pk2  = ws + 24576;

        k2_partial<<<dim3(K_/256, 8), 256, 0, stream>>>(kmat, pk2);
        k2_reduce <<<K_/256, 256, 0, stream>>>(pk2, k2);
        x2_kernel <<<B_, 256, 0, stream>>>(x, x2);
        gemm_norms<<<dim3(K_/BN, B_/BM), 256, 0, stream>>>(x, kmat, x2, k2, out);
        rowscan   <<<B_, 256, 0, stream>>>(out, x, kmat, widx);
        finalize  <<<(size_t)B_ * (K_/4) / 256, 256, 0, stream>>>(out, widx, sigma);
    }
}

// Round 17
// 414.942 us; speedup vs baseline: 1.1525x; 1.1525x over previous
//
#include <hip/hip_runtime.h>
#include <math.h>

// Problem constants
#define B_    4096
#define D_    2048
#define K_    16384
#define SIDE  128

// f32-fallback GEMM tiling
#define BM 128
#define BN 128
#define BD 16
#define ASTR 132

// Argmin refinement
#define EPS_CAND 0.04f
#define MARGIN   0.015f
#define MAXCAND  64
#define RMAX     12

// GEMM (round-8/15 best): BK=64, 2x(2-half) LDS regions, one barrier per tile
#define NKT 32   // 2048 / 64

typedef __attribute__((ext_vector_type(8))) short bf16x8;
typedef __attribute__((ext_vector_type(4))) float f32x4;

__device__ __forceinline__ short bf16_rne(float f) {
    unsigned u = __float_as_uint(f);
    unsigned r = u + 0x7FFFu + ((u >> 16) & 1u);
    return (short)(r >> 16);
}

__device__ __forceinline__ void gload16(const void* g, void* l) {
    __builtin_amdgcn_global_load_lds(
        (const __attribute__((address_space(1))) unsigned int*)g,
        (__attribute__((address_space(3))) unsigned int*)l, 16, 0, 0);
}

// ---------------- pack kernel -> Bt (bf16 transposed) + k2 partials, fused ----------------
__global__ __launch_bounds__(256) void pack_bt_k2(const float* __restrict__ kmat,
                                                  short* __restrict__ Bt,
                                                  float* __restrict__ pk2b) {
    __shared__ float tile[64][65];
    const int n0 = blockIdx.x * 64, d0 = blockIdx.y * 64;
    const int t = threadIdx.x;
    const int lr = t >> 4, lc4 = (t & 15) * 4;
    #pragma unroll
    for (int r = 0; r < 4; ++r) {
        float4 v = *(const float4*)&kmat[(size_t)(d0 + lr + r*16) * K_ + n0 + lc4];
        tile[lr + r*16][lc4 + 0] = v.x;
        tile[lr + r*16][lc4 + 1] = v.y;
        tile[lr + r*16][lc4 + 2] = v.z;
        tile[lr + r*16][lc4 + 3] = v.w;
    }
    __syncthreads();
    const int n = t >> 2, dc = (t & 3) * 16;
    short tmp[16];
    float s = 0.f;
    #pragma unroll
    for (int i = 0; i < 16; ++i) {
        float v = tile[dc + i][n];
        tmp[i] = bf16_rne(v);
        s = fmaf(v, v, s);
    }
    short* dst = &Bt[(size_t)(n0 + n) * 2048 + d0 + dc];
    *(int4*)dst       = *(const int4*)tmp;
    *(int4*)(dst + 8) = *(const int4*)(tmp + 8);
    s += __shfl_xor(s, 1);
    s += __shfl_xor(s, 2);
    if ((t & 3) == 0) pk2b[(size_t)(d0 >> 6) * K_ + n0 + n] = s;
}

// ---------------- fused: pack x -> Ah + x2 (blocks < 4096) | k2 reduce (blocks >= 4096) ----
__global__ __launch_bounds__(256) void pack_a_k2(const float* __restrict__ x,
                                                 short* __restrict__ Ah,
                                                 float* __restrict__ x2,
                                                 const float* __restrict__ pk2b,
                                                 float* __restrict__ k2) {
    const int b = blockIdx.x;
    const int t = threadIdx.x;
    if (b < B_) {
        const size_t i = (size_t)b * 2048 + (size_t)t * 8;
        float4 v0 = *(const float4*)&x[i];
        float4 v1 = *(const float4*)&x[i + 4];
        short tmp[8] = { bf16_rne(v0.x), bf16_rne(v0.y), bf16_rne(v0.z), bf16_rne(v0.w),
                         bf16_rne(v1.x), bf16_rne(v1.y), bf16_rne(v1.z), bf16_rne(v1.w) };
        *(int4*)&Ah[i] = *(const int4*)tmp;
        float s = v0.x*v0.x + v0.y*v0.y + v0.z*v0.z + v0.w*v0.w
                + v1.x*v1.x + v1.y*v1.y + v1.z*v1.z + v1.w*v1.w;
        __shared__ float red[256];
        red[t] = s; __syncthreads();
        for (int off = 128; off > 0; off >>= 1) {
            if (t < off) red[t] += red[t + off];
            __syncthreads();
        }
        if (t == 0) x2[b] = red[0];
    } else {
        const int k = (b - B_) * 256 + t;
        float s = 0.f;
        #pragma unroll
        for (int j = 0; j < 32; ++j) s += pk2b[(size_t)j * K_ + k];
        k2[k] = s;
    }
}

// ---------------- pipelined 256x256 bf16 MFMA GEMM -> norms2 -> d_out + pmin ----------------
// Round-8 structure: BK=64 (two 32-wide halves per region pair), one barrier per
// K-tile; ds_reads (ksub0 | ksub1) + next-tile staging issued up front,
// compiler-counted lgkmcnt overlaps ksub1 reads + staging with MFMA ksub0.
// pmin layout: [64 n-blocks][4096 rows]
__global__ __launch_bounds__(512, 2) void gemm_8ph(
    const short* __restrict__ Ah, const short* __restrict__ Bt,
    const float* __restrict__ x2, const float* __restrict__ k2,
    float* __restrict__ out, float* __restrict__ pmin)
{
    __shared__ short As[4 * 8192];
    __shared__ short Bs[4 * 8192];

    const int tid = threadIdx.x;
    const int lane = tid & 63;
    const int w = tid >> 6;
    const int wm = w >> 2, wn = w & 3;
    const int lrow = lane & 15, lkg = lane >> 4;

    // XCD-aware swizzle: 1024 blocks = 8 xcds x (8 bn-chunk x 16 bm)
    const int orig = blockIdx.x;
    const int xcd = orig & 7, seq = orig >> 3;
    const int bn0 = (xcd * 8 + (seq & 7)) * 256;
    const int bm0 = (seq >> 3) * 256;

    const int csw = ((tid & 3) ^ ((tid >> 3) & 3)) * 8;   // pre-swizzled source chunk
    const short* pA = Ah + (size_t)(bm0 + (tid >> 2)) * 2048 + csw;
    const short* pB = Bt + (size_t)(bn0 + (tid >> 2)) * 2048 + csw;
    const int ldsT = tid * 8;

    const int rsw = (lkg ^ ((lrow >> 1) & 3)) * 8;        // read-side swizzle
    const int aBase = (wm * 128 + lrow) * 32 + rsw;
    const int bBase = (wn * 64 + lrow) * 32 + rsw;

    f32x4 acc[8][4];
    #pragma unroll
    for (int i = 0; i < 8; ++i)
        #pragma unroll
        for (int j = 0; j < 4; ++j) acc[i][j] = (f32x4){0.f, 0.f, 0.f, 0.f};

#define STAGE(MATL, PTR, KS, T) do { \
    short* _l = (MATL) + ((((T) & 1) * 2 + (KS)) * 8192) + ldsT; \
    const short* _g = (PTR) + (size_t)(T) * 64 + (KS) * 32; \
    gload16(_g, _l); \
    gload16(_g + (size_t)128 * 2048, _l + 4096); \
} while (0)

    // prologue: stage tile 0 (both ksub halves of A and B), drain, barrier
    STAGE(As, pA, 0, 0); STAGE(As, pA, 1, 0);
    STAGE(Bs, pB, 0, 0); STAGE(Bs, pB, 1, 0);
    asm volatile("s_waitcnt vmcnt(0)" ::: "memory");
    __builtin_amdgcn_s_barrier();

    for (int t = 0; t < NKT; ++t) {
        const int rg = (t & 1) * 2;
        const short* Ar0 = &As[rg * 8192];
        const short* Br0 = &Bs[rg * 8192];
        const short* Ar1 = Ar0 + 8192;
        const short* Br1 = Br0 + 8192;
        bf16x8 a0[8], b0[4], a1[8], b1[4];

        // group 0 reads (ksub0)
        #pragma unroll
        for (int mf = 0; mf < 8; ++mf) a0[mf] = *(const bf16x8*)&Ar0[aBase + mf * 512];
        #pragma unroll
        for (int nf = 0; nf < 4; ++nf) b0[nf] = *(const bf16x8*)&Br0[bBase + nf * 512];
        __builtin_amdgcn_sched_barrier(0);
        // group 1 reads (ksub1) + next-tile staging — overlap MFMA ksub0
        #pragma unroll
        for (int mf = 0; mf < 8; ++mf) a1[mf] = *(const bf16x8*)&Ar1[aBase + mf * 512];
        #pragma unroll
        for (int nf = 0; nf < 4; ++nf) b1[nf] = *(const bf16x8*)&Br1[bBase + nf * 512];
        if (t + 1 < NKT) {
            STAGE(As, pA, 0, t + 1); STAGE(As, pA, 1, t + 1);
            STAGE(Bs, pB, 0, t + 1); STAGE(Bs, pB, 1, t + 1);
        }
        __builtin_amdgcn_sched_barrier(0);

        __builtin_amdgcn_s_setprio(1);
        #pragma unroll
        for (int mf = 0; mf < 8; ++mf) {
            acc[mf][0] = __builtin_amdgcn_mfma_f32_16x16x32_bf16(a0[mf], b0[0], acc[mf][0], 0, 0, 0);
            acc[mf][1] = __builtin_amdgcn_mfma_f32_16x16x32_bf16(a0[mf], b0[1], acc[mf][1], 0, 0, 0);
            acc[mf][2] = __builtin_amdgcn_mfma_f32_16x16x32_bf16(a0[mf], b0[2], acc[mf][2], 0, 0, 0);
            acc[mf][3] = __builtin_amdgcn_mfma_f32_16x16x32_bf16(a0[mf], b0[3], acc[mf][3], 0, 0, 0);
        }
        __builtin_amdgcn_sched_barrier(0);
        #pragma unroll
        for (int mf = 0; mf < 8; ++mf) {
            acc[mf][0] = __builtin_amdgcn_mfma_f32_16x16x32_bf16(a1[mf], b1[0], acc[mf][0], 0, 0, 0);
            acc[mf][1] = __builtin_amdgcn_mfma_f32_16x16x32_bf16(a1[mf], b1[1], acc[mf][1], 0, 0, 0);
            acc[mf][2] = __builtin_amdgcn_mfma_f32_16x16x32_bf16(a1[mf], b1[2], acc[mf][2], 0, 0, 0);
            acc[mf][3] = __builtin_amdgcn_mfma_f32_16x16x32_bf16(a1[mf], b1[3], acc[mf][3], 0, 0, 0);
        }
        __builtin_amdgcn_s_setprio(0);
        __builtin_amdgcn_sched_barrier(0);
        asm volatile("s_waitcnt vmcnt(0)" ::: "memory");
        __builtin_amdgcn_s_barrier();
    }
#undef STAGE

    // ---- epilogue: norms2 scalar stores + register/shfl per-row block-min ----
    // C/D frag: col = lane&15, row = (lane>>4)*4 + j
    const int r0 = bm0 + wm * 128 + lkg * 4;
    const int c0 = bn0 + wn * 64 + lrow;
    float kc[4];
    #pragma unroll
    for (int nf = 0; nf < 4; ++nf) kc[nf] = k2[c0 + nf * 16];

    float* sm2 = (float*)As;   // [4 wn][256 rows] = 4 KB, reuse staging LDS
    __syncthreads();

    #pragma unroll
    for (int mf = 0; mf < 8; ++mf) {
        #pragma unroll
        for (int jj = 0; jj < 4; ++jj) {
            const int gr = r0 + mf * 16 + jj;
            const float xv = x2[gr];
            float* orow = out + (size_t)gr * K_ + c0;
            float v0 = fmaxf((xv - 2.f * acc[mf][0][jj]) + kc[0], 0.f);
            float v1 = fmaxf((xv - 2.f * acc[mf][1][jj]) + kc[1], 0.f);
            float v2 = fmaxf((xv - 2.f * acc[mf][2][jj]) + kc[2], 0.f);
            float v3 = fmaxf((xv - 2.f * acc[mf][3][jj]) + kc[3], 0.f);
            orow[0]  = v0;
            orow[16] = v1;
            orow[32] = v2;
            orow[48] = v3;
            float m = fminf(fminf(v0, v1), fminf(v2, v3));
            m = fminf(m, __shfl_xor(m, 1));
            m = fminf(m, __shfl_xor(m, 2));
            m = fminf(m, __shfl_xor(m, 4));
            m = fminf(m, __shfl_xor(m, 8));
            if (lrow == 0)
                sm2[wn * 256 + wm * 128 + mf * 16 + lkg * 4 + jj] = m;
        }
    }
    __syncthreads();
    if (tid < 256) {
        float m = fminf(fminf(sm2[tid], sm2[256 + tid]),
                        fminf(sm2[512 + tid], sm2[768 + tid]));
        pmin[(size_t)(bn0 >> 8) * 4096 + bm0 + tid] = m;
    }
}

// ---------------- fused rowmin/candidates/refine + patch-radial write ----------------
__global__ __launch_bounds__(256) void rowpost(
    float* __restrict__ out, const float* __restrict__ X,
    const float* __restrict__ Kmat, const float* __restrict__ pmin,
    const float* __restrict__ sigma)
{
    const int row = blockIdx.x;
    const int t = threadIdx.x;
    float* orow = out + (size_t)row * K_;

    __shared__ float sblk[64];
    __shared__ float sgmin;
    __shared__ int scnt, swidx, needRefine;
    __shared__ int cand[MAXCAND];
    __shared__ float cval[MAXCAND];
    __shared__ double sred[256];
    __shared__ float cscore[MAXCAND];
    __shared__ float patch[(2*RMAX+1)*(2*RMAX+1)];

    if (t < 64) sblk[t] = pmin[(size_t)t * 4096 + row];
    if (t == 0) scnt = 0;
    __syncthreads();
    if (t == 0) {
        float m = sblk[0];
        for (int i = 1; i < 64; ++i) m = fminf(m, sblk[i]);
        sgmin = m;
    }
    __syncthreads();
    const float thr = sgmin + EPS_CAND;

    // candidate collection: only blocks whose min can reach thr
    for (int b = 0; b < 64; ++b) {
        if (sblk[b] <= thr) {
            float v = orow[b * 256 + t];
            if (v <= thr) {
                int p = atomicAdd(&scnt, 1);
                if (p < MAXCAND) { cand[p] = b * 256 + t; cval[p] = v; }
            }
        }
    }
    __syncthreads();
    const int cnt = min(scnt, MAXCAND);

    if (cnt == 1) {
        if (t == 0) { swidx = cand[0]; needRefine = 0; }
        __syncthreads();
    } else {
        // stored-margin test: if stored best leads by > MARGIN, it is the gold winner
        if (t == 0) {
            float bv = cval[0]; int bi = cand[0];
            for (int c = 1; c < cnt; ++c)
                if (cval[c] < bv || (cval[c] == bv && cand[c] < bi)) { bv = cval[c]; bi = cand[c]; }
            float sv = 3.4e38f;
            for (int c = 0; c < cnt; ++c)
                if (cand[c] != bi) sv = fminf(sv, cval[c]);
            if (sv - bv > MARGIN) { swidx = bi; needRefine = 0; }
            else needRefine = 1;
        }
        __syncthreads();
        if (needRefine) {
            // gold emulation: each primitive exact-f64, then f32-rounded
            const float* xrow = X + (size_t)row * D_;
            double xs = 0.0;
            for (int d = t; d < D_; d += 256) {
                float xv = xrow[d];
                float sq = xv * xv;
                xs += (double)sq;
            }
            sred[t] = xs; __syncthreads();
            for (int off = 128; off > 0; off >>= 1) {
                if (t < off) sred[t] += sred[t + off];
                __syncthreads();
            }
            const float x2f = (float)sred[0];
            __syncthreads();

            for (int c = 0; c < cnt; ++c) {
                const int k = cand[c];
                double dt = 0.0, kk = 0.0;
                for (int d = t; d < D_; d += 256) {
                    float wv = Kmat[(size_t)d * K_ + k];
                    float xv = xrow[d];
                    dt += (double)xv * (double)wv;
                    float w2 = wv * wv;
                    kk += (double)w2;
                }
                sred[t] = dt; __syncthreads();
                for (int off = 128; off > 0; off >>= 1) {
                    if (t < off) sred[t] += sred[t + off];
                    __syncthreads();
                }
                const float dotf = (float)sred[0];
                __syncthreads();
                sred[t] = kk; __syncthreads();
                for (int off = 128; off > 0; off >>= 1) {
                    if (t < off) sred[t] += sred[t + off];
                    __syncthreads();
                }
                if (t == 0) {
                    const float k2f = (float)sred[0];
                    cscore[c] = fmaxf((x2f - 2.0f * dotf) + k2f, 0.0f);
                }
                __syncthreads();
            }
            if (t == 0) {
                float bv = cscore[0]; int bi = cand[0];
                for (int c = 1; c < cnt; ++c) {
                    if (cscore[c] < bv || (cscore[c] == bv && cand[c] < bi)) {
                        bv = cscore[c]; bi = cand[c];
                    }
                }
                swidx = bi;
            }
            __syncthreads();
        }
    }

    // ---- radial write: values outside radius R are < 0.5 -> write zeros, skip read ----
    const int wi = swidx;
    const int wx = wi >> 7, wy = wi & 127;
    const float sg = sigma[0];
    const float ninv  = -0.5f / (sg * sg);
    const float scale = 1.0f / (sg * sqrtf(2.0f * 3.14159265358979323846f));
    // drop bound: scale*exp(-R^2/(2 sg^2))*4096 <= 0.5
    float larg = 8192.0f * scale;
    int R = (larg <= 1.0f) ? 0
          : (int)ceilf(sg * sqrtf(2.0f * logf(larg)));

    if (R <= RMAX) {
        const int W = 2 * R + 1;
        for (int p = t; p < W * W; p += 256) {
            int dx = p / W - R, dy = p % W - R;
            int gx = wx + dx, gy = wy + dy;
            if ((unsigned)gx < 128u && (unsigned)gy < 128u)
                patch[p] = orow[gx * 128 + gy];
        }
        __syncthreads();
        for (int i = t; i < K_ / 4; i += 256) {
            const int k0 = i * 4;
            const int gx = k0 >> 7;
            const int dx = gx - wx;
            float4 v = make_float4(0.f, 0.f, 0.f, 0.f);
            float* vp = (float*)&v;
            if (dx >= -R && dx <= R) {
                #pragma unroll
                for (int j = 0; j < 4; ++j) {
                    int gy = (k0 & 127) + j;
                    int dy = gy - wy;
                    if (dy >= -R && dy <= R) {
                        float d2 = (float)(dx * dx + dy * dy);
                        vp[j] = patch[(dx + R) * W + (dy + R)] * (scale * __expf(ninv * d2));
                    }
                }
            }
            *(float4*)&orow[k0] = v;
        }
    } else {
        // general-sigma fallback: full read-modify-write
        for (int i = t; i < K_ / 4; i += 256) {
            float4 v = ((const float4*)orow)[i];
            float* vp = (float*)&v;
            #pragma unroll
            for (int j = 0; j < 4; ++j) {
                int k = i * 4 + j;
                float gx = (float)(k >> 7), gy = (float)(k & 127);
                float dx = gx - (float)wx, dy = gy - (float)wy;
                float d2 = dx * dx + dy * dy;
                vp[j] = vp[j] * (__expf(ninv * d2) * scale);
            }
            ((float4*)orow)[i] = v;
        }
    }
}

// ================= f32 fallback path (unchanged round-3 kernels) =================
__global__ void k2_partial(const float* __restrict__ kmat, float* __restrict__ pk2) {
    int k  = blockIdx.x * 256 + threadIdx.x;
    int d0 = blockIdx.y * 256;
    float s = 0.f;
    #pragma unroll 8
    for (int d = 0; d < 256; ++d) {
        float v = kmat[(size_t)(d0 + d) * K_ + k];
        s = fmaf(v, v, s);
    }
    pk2[(size_t)blockIdx.y * K_ + k] = s;
}

__global__ void k2_reduce(const float* __restrict__ pk2, float* __restrict__ k2) {
    int k = blockIdx.x * 256 + threadIdx.x;
    float s = 0.f;
    #pragma unroll
    for (int j = 0; j < 8; ++j) s += pk2[(size_t)j * K_ + k];
    k2[k] = s;
}

__global__ void x2_kernel(const float* __restrict__ x, float* __restrict__ x2) {
    int row = blockIdx.x;
    const float* xr = x + (size_t)row * D_;
    int t = threadIdx.x;
    float4 v0 = ((const float4*)xr)[t];
    float4 v1 = ((const float4*)xr)[t + 256];
    float s = v0.x*v0.x + v0.y*v0.y + v0.z*v0.z + v0.w*v0.w
            + v1.x*v1.x + v1.y*v1.y + v1.z*v1.z + v1.w*v1.w;
    __shared__ float red[256];
    red[t] = s; __syncthreads();
    for (int off = 128; off > 0; off >>= 1) {
        if (t < off) red[t] += red[t + off];
        __syncthreads();
    }
    if (t == 0) x2[row] = red[0];
}

__global__ __launch_bounds__(256) void gemm_norms(
    const float* __restrict__ X, const float* __restrict__ Kmat,
    const float* __restrict__ x2, const float* __restrict__ k2,
    float* __restrict__ out)
{
    __shared__ float Asf[BD * ASTR];
    __shared__ float Bsf[BD * BN];

    const int tid = threadIdx.x;
    const int tx = tid & 15, ty = tid >> 4;
    const int bn0 = blockIdx.x * BN;
    const int bm0 = blockIdx.y * BM;

    float acc[8][8];
    #pragma unroll
    for (int i = 0; i < 8; ++i)
        #pragma unroll
        for (int j = 0; j < 8; ++j) acc[i][j] = 0.f;

    const int lm = tid >> 2;
    const int ld = (tid & 3) << 2;
    const int bd = tid >> 5;
    const int bk = (tid & 31) << 2;

    const float* Xp = X    + (size_t)(bm0 + lm) * D_ + ld;
    const float* Kp = Kmat + (size_t)bd * K_ + bn0 + bk;

    float4 a0 = *(const float4*)(Xp);
    float4 a1 = *(const float4*)(Xp + (size_t)64 * D_);
    float4 b0 = *(const float4*)(Kp);
    float4 b1 = *(const float4*)(Kp + (size_t)8 * K_);

    const int NT = D_ / BD;
    for (int kt = 0; kt < NT; ++kt) {
        __syncthreads();
        Asf[(ld+0)*ASTR + lm]      = a0.x;
        Asf[(ld+1)*ASTR + lm]      = a0.y;
        Asf[(ld+2)*ASTR + lm]      = a0.z;
        Asf[(ld+3)*ASTR + lm]      = a0.w;
        Asf[(ld+0)*ASTR + lm + 64] = a1.x;
        Asf[(ld+1)*ASTR + lm + 64] = a1.y;
        Asf[(ld+2)*ASTR + lm + 64] = a1.z;
        Asf[(ld+3)*ASTR + lm + 64] = a1.w;
        *(float4*)&Bsf[bd*BN + bk]     = b0;
        *(float4*)&Bsf[(bd+8)*BN + bk] = b1;
        __syncthreads();

        if (kt + 1 < NT) {
            const float* Xn = Xp + (kt + 1) * BD;
            const float* Kn = Kp + (size_t)(kt + 1) * BD * K_;
            a0 = *(const float4*)(Xn);
            a1 = *(const float4*)(Xn + (size_t)64 * D_);
            b0 = *(const float4*)(Kn);
            b1 = *(const float4*)(Kn + (size_t)8 * K_);
        }

        #pragma unroll
        for (int dd = 0; dd < BD; ++dd) {
            float4 A0 = *(const float4*)&Asf[dd*ASTR + ty*4];
            float4 A1 = *(const float4*)&Asf[dd*ASTR + ty*4 + 64];
            float4 B0 = *(const float4*)&Bsf[dd*BN + tx*4];
            float4 B1 = *(const float4*)&Bsf[dd*BN + tx*4 + 64];
            float a[8] = {A0.x,A0.y,A0.z,A0.w,A1.x,A1.y,A1.z,A1.w};
            float b[8] = {B0.x,B0.y,B0.z,B0.w,B1.x,B1.y,B1.z,B1.w};
            #pragma unroll
            for (int i = 0; i < 8; ++i)
                #pragma unroll
                for (int j = 0; j < 8; ++j)
                    acc[i][j] = fmaf(a[i], b[j], acc[i][j]);
        }
    }

    int rl[8], cl[8];
    #pragma unroll
    for (int i = 0; i < 4; ++i) {
        rl[i] = ty*4 + i;  rl[i+4] = ty*4 + 64 + i;
        cl[i] = tx*4 + i;  cl[i+4] = tx*4 + 64 + i;
    }
    float xr[8], kc[8];
    #pragma unroll
    for (int i = 0; i < 8; ++i) { xr[i] = x2[bm0 + rl[i]]; kc[i] = k2[bn0 + cl[i]]; }

    #pragma unroll
    for (int i = 0; i < 8; ++i) {
        float vv[8];
        #pragma unroll
        for (int j = 0; j < 8; ++j)
            vv[j] = fmaxf((xr[i] - 2.f * acc[i][j]) + kc[j], 0.f);
        int gr = bm0 + rl[i];
        *(float4*)&out[(size_t)gr * K_ + bn0 + tx*4]      = make_float4(vv[0],vv[1],vv[2],vv[3]);
        *(float4*)&out[(size_t)gr * K_ + bn0 + tx*4 + 64] = make_float4(vv[4],vv[5],vv[6],vv[7]);
    }
}

__global__ __launch_bounds__(256) void rowscan(
    const float* __restrict__ out, const float* __restrict__ X,
    const float* __restrict__ Kmat, int* __restrict__ widx)
{
    const int row = blockIdx.x;
    const int t = threadIdx.x;
    const float* orow = out + (size_t)row * K_;

    float mn = 3.4e38f;
    for (int i = t; i < K_/4; i += 256) {
        float4 v = ((const float4*)orow)[i];
        mn = fminf(mn, fminf(fminf(v.x, v.y), fminf(v.z, v.w)));
    }
    __shared__ float smin[256];
    smin[t] = mn; __syncthreads();
    for (int off = 128; off > 0; off >>= 1) {
        if (t < off) smin[t] = fminf(smin[t], smin[t+off]);
        __syncthreads();
    }
    const float rowmin = smin[0];

    __shared__ int scnt;
    __shared__ int cand[MAXCAND];
    if (t == 0) scnt = 0;
    __syncthreads();
    const float thr = rowmin + EPS_CAND;
    for (int i = t; i < K_/4; i += 256) {
        float4 v = ((const float4*)orow)[i];
        float vv[4] = {v.x, v.y, v.z, v.w};
        #pragma unroll
        for (int j = 0; j < 4; ++j) {
            if (vv[j] <= thr) {
                int p = atomicAdd(&scnt, 1);
                if (p < MAXCAND) cand[p] = i*4 + j;
            }
        }
    }
    __syncthreads();
    const int cnt = min(scnt, MAXCAND);
    if (cnt == 1) {
        if (t == 0) widx[row] = cand[0];
        return;
    }

    const float* xrow = X + (size_t)row * D_;
    __shared__ double sred[256];
    double xs = 0.0;
    for (int d = t; d < D_; d += 256) {
        float xv = xrow[d];
        float sq = xv * xv;
        xs += (double)sq;
    }
    sred[t] = xs; __syncthreads();
    for (int off = 128; off > 0; off >>= 1) {
        if (t < off) sred[t] += sred[t+off];
        __syncthreads();
    }
    const float x2f = (float)sred[0];
    __syncthreads();

    __shared__ float cscore[MAXCAND];
    for (int c = 0; c < cnt; ++c) {
        const int k = cand[c];
        double dt = 0.0, kk = 0.0;
        for (int d = t; d < D_; d += 256) {
            float wv = Kmat[(size_t)d * K_ + k];
            float xv = xrow[d];
            dt += (double)xv * (double)wv;
            float w2 = wv * wv;
            kk += (double)w2;
        }
        sred[t] = dt; __syncthreads();
        for (int off = 128; off > 0; off >>= 1) {
            if (t < off) sred[t] += sred[t+off];
            __syncthreads();
        }
        const float dotf = (float)sred[0];
        __syncthreads();
        sred[t] = kk; __syncthreads();
        for (int off = 128; off > 0; off >>= 1) {
            if (t < off) sred[t] += sred[t+off];
            __syncthreads();
        }
        if (t == 0) {
            const float k2f = (float)sred[0];
            cscore[c] = fmaxf((x2f - 2.0f * dotf) + k2f, 0.0f);
        }
        __syncthreads();
    }
    if (t == 0) {
        float bv = cscore[0]; int bi = cand[0];
        for (int c = 1; c < cnt; ++c) {
            if (cscore[c] < bv || (cscore[c] == bv && cand[c] < bi)) {
                bv = cscore[c]; bi = cand[c];
            }
        }
        widx[row] = bi;
    }
}

__global__ void finalize(float* __restrict__ out, const int* __restrict__ widx,
                         const float* __restrict__ sigma) {
    size_t gid = (size_t)blockIdx.x * blockDim.x + threadIdx.x;
    int row = (int)(gid / (K_ / 4));
    int c4  = (int)(gid % (K_ / 4)) * 4;
    int w = widx[row];
    float wx = (float)(w >> 7), wy = (float)(w & 127);
    float sg = sigma[0];
    float ninv  = -0.5f / (sg * sg);
    float scale = 1.0f / (sg * sqrtf(2.0f * 3.14159265358979323846f));
    float4 v = *(float4*)&out[(size_t)row * K_ + c4];
    float* vp = (float*)&v;
    #pragma unroll
    for (int j = 0; j < 4; ++j) {
        int k = c4 + j;
        float gx = (float)(k >> 7), gy = (float)(k & 127);
        float dx = gx - wx, dy = gy - wy;
        float d2 = dx*dx + dy*dy;
        vp[j] = vp[j] * (__expf(ninv * d2) * scale);
    }
    *(float4*)&out[(size_t)row * K_ + c4] = v;
}

extern "C" void kernel_launch(void* const* d_in, const int* in_sizes, int n_in,
                              void* d_out, int out_size, void* d_ws, size_t ws_size,
                              hipStream_t stream) {
    const float* x     = (const float*)d_in[0];
    const float* kmat  = (const float*)d_in[1];
    const float* sigma = (const float*)d_in[2];
    float* out = (float*)d_out;

    const size_t BT_BYTES = (size_t)K_ * D_ * 2;   // 64 MB
    const size_t AH_BYTES = (size_t)B_ * D_ * 2;   // 16 MB
    // floats after Bt|Ah: k2[16384] x2[4096] pk2b[32*16384] pmin[64*4096]
    const size_t WS_NEED  = BT_BYTES + AH_BYTES +
        (size_t)(16384 + 4096 + 32*16384 + 64*4096) * 4;

    if (ws_size >= WS_NEED) {
        short* Bt   = (short*)d_ws;
        short* Ahp  = (short*)((char*)d_ws + BT_BYTES);
        float* k2   = (float*)((char*)d_ws + BT_BYTES + AH_BYTES);
        float* x2   = k2 + 16384;
        float* pk2b = x2 + 4096;
        float* pmin = pk2b + 32*16384;

        pack_bt_k2<<<dim3(K_/64, D_/64), 256, 0, stream>>>(kmat, Bt, pk2b);
        pack_a_k2 <<<B_ + K_/256, 256, 0, stream>>>(x, Ahp, x2, pk2b, k2);
        gemm_8ph  <<<1024, 512, 0, stream>>>(Ahp, Bt, x2, k2, out, pmin);
        rowpost   <<<B_, 256, 0, stream>>>(out, x, kmat, pmin, sigma);
    } else {
        float* ws = (float*)d_ws;
        float* k2   = ws;
        float* x2   = ws + 16384;
        int*   widx = (int*)(ws + 20480);
        float* pk2  = ws + 24576;

        k2_partial<<<dim3(K_/256, 8), 256, 0, stream>>>(kmat, pk2);
        k2_reduce <<<K_/256, 256, 0, stream>>>(pk2, k2);
        x2_kernel <<<B_, 256, 0, stream>>>(x, x2);
        gemm_norms<<<dim3(K_/BN, B_/BM), 256, 0, stream>>>(x, kmat, x2, k2, out);
        rowscan   <<<B_, 256, 0, stream>>>(out, x, kmat, widx);
        finalize  <<<(size_t)B_ * (K_/4) / 256, 256, 0, stream>>>(out, widx, sigma);
    }
}